// Round 1
// baseline (4666.267 us; speedup 1.0000x reference)
//
#include <hip/hip_runtime.h>
#include <cstddef>

#define BATCH   4096
#define DXP     32
#define DIM3    96
#define NSTEPS  100
#define HID     256
#define NE      16      // batch elements per block
#define SH      20      // padded LDS stride for h1/h2 (breaks bank conflicts, keeps float4 align)
#define SX      16      // LDS stride for positions

#define PIO2F   1.57079632679489662f

// ---------------- MLP layer, N=256 outputs, K=96 or 256 ----------------
// in_lds:  [k][e] k-major, stride in_stride
// out_lds: [j][e] j-major, stride SH, tanh applied
__device__ __forceinline__ void layer256(
    int K, const float* __restrict__ W, const float* __restrict__ bias,
    const float* __restrict__ in_lds, int in_stride,
    float* __restrict__ out_lds, float* __restrict__ wbuf, int tid)
{
    const int jg = tid & 63;          // wave-lane -> j group (full wave shares e-group)
    const int eg = tid >> 6;
    const int j0 = jg << 2;
    const int e0 = eg << 2;

    float acc[4][4];
    #pragma unroll
    for (int ee = 0; ee < 4; ++ee)
        #pragma unroll
        for (int jj = 0; jj < 4; ++jj) acc[ee][jj] = 0.f;

    const int nc = K >> 4;            // 16-row chunks
    const float4* __restrict__ Wv = (const float4*)W;
    float4* wv = (float4*)wbuf;

    float4 pre[4];
    #pragma unroll
    for (int i = 0; i < 4; ++i) pre[i] = Wv[tid + i*256];

    for (int c = 0; c < nc; ++c) {
        __syncthreads();              // prior chunk fully consumed
        #pragma unroll
        for (int i = 0; i < 4; ++i) wv[tid + i*256] = pre[i];
        if (c + 1 < nc) {             // prefetch next chunk (latency overlaps compute)
            #pragma unroll
            for (int i = 0; i < 4; ++i) pre[i] = Wv[(c+1)*1024 + tid + i*256];
        }
        __syncthreads();              // chunk visible
        const float* inb = in_lds + (c << 4) * in_stride + e0;
        #pragma unroll
        for (int kk = 0; kk < 16; ++kk) {
            const float4 a = *(const float4*)(inb + kk * in_stride);   // LDS broadcast (1 addr/wave)
            const float4 w = *(const float4*)(wbuf + kk*256 + j0);     // contiguous, conflict-free
            const float av[4] = {a.x, a.y, a.z, a.w};
            const float wl[4] = {w.x, w.y, w.z, w.w};
            #pragma unroll
            for (int ee = 0; ee < 4; ++ee)
                #pragma unroll
                for (int jj = 0; jj < 4; ++jj)
                    acc[ee][jj] += av[ee] * wl[jj];
        }
    }

    const float4 bb = *(const float4*)(bias + j0);
    const float bv[4] = {bb.x, bb.y, bb.z, bb.w};
    #pragma unroll
    for (int jj = 0; jj < 4; ++jj) {
        float4 v;
        v.x = tanhf(acc[0][jj] + bv[jj]);
        v.y = tanhf(acc[1][jj] + bv[jj]);
        v.z = tanhf(acc[2][jj] + bv[jj]);
        v.w = tanhf(acc[3][jj] + bv[jj]);
        *(float4*)(out_lds + (j0 + jj) * SH + e0) = v;
    }
}

// ---------------- layer 3: K=256 -> N=96, no tanh, output e-major gbuf[e*96+o] ----------------
__device__ __forceinline__ void layer3(
    const float* __restrict__ W, const float* __restrict__ bias,
    const float* __restrict__ h2, float* __restrict__ wbuf,
    float* __restrict__ gbuf, int tid)
{
    const int og = tid & 31;
    const int eg = tid >> 5;
    const int o0 = og * 3;
    const int e0 = eg << 1;

    float acc[2][3];
    #pragma unroll
    for (int ee = 0; ee < 2; ++ee)
        #pragma unroll
        for (int oo = 0; oo < 3; ++oo) acc[ee][oo] = 0.f;

    const float2* __restrict__ Wv = (const float2*)W;
    float2* wv2 = (float2*)wbuf;

    float2 pre[3];
    #pragma unroll
    for (int i = 0; i < 3; ++i) pre[i] = Wv[tid + i*256];

    for (int c = 0; c < 16; ++c) {
        __syncthreads();
        #pragma unroll
        for (int i = 0; i < 3; ++i) wv2[tid + i*256] = pre[i];
        if (c + 1 < 16) {
            #pragma unroll
            for (int i = 0; i < 3; ++i) pre[i] = Wv[(c+1)*768 + tid + i*256];
        }
        __syncthreads();
        #pragma unroll
        for (int kk = 0; kk < 16; ++kk) {
            const float2 a = *(const float2*)(h2 + (c*16 + kk)*SH + e0);
            const float* wr = wbuf + kk*96 + o0;
            const float w0 = wr[0], w1 = wr[1], w2 = wr[2];
            acc[0][0] += a.x*w0; acc[0][1] += a.x*w1; acc[0][2] += a.x*w2;
            acc[1][0] += a.y*w0; acc[1][1] += a.y*w1; acc[1][2] += a.y*w2;
        }
    }
    __syncthreads();   // all wbuf chunk reads done before gbuf (aliases wbuf) is written
    #pragma unroll
    for (int ee = 0; ee < 2; ++ee)
        #pragma unroll
        for (int oo = 0; oo < 3; ++oo)
            gbuf[(e0 + ee)*96 + o0 + oo] = acc[ee][oo] + bias[o0 + oo];
    __syncthreads();   // gbuf visible for particle stage
}

// ---------------- particle / SDE update for one step ----------------
__device__ __forceinline__ void particles_step(
    int t, int b0, const float* __restrict__ dBt,
    float s2d0, float s2d1, float sqdt,
    float* __restrict__ xsT, const float* __restrict__ gbuf,
    float* __restrict__ sP, float* __restrict__ sRun, float* __restrict__ sRel,
    int tid)
{
#pragma clang fp contract(off)
    const int e  = tid >> 4;
    const int tt = tid & 15;
    const int b  = b0 + e;
    const float runf = sRun[e];
    float dpsum = 0.f, psum = 0.f;
    int hit = 0;
    #pragma unroll
    for (int pp = 0; pp < 2; ++pp) {
        const int p = tt + (pp << 4);
        const float s2d = pp ? s2d1 : s2d0;
        const float2 db = *(const float2*)(dBt + (((size_t)t*BATCH + b)*DXP + p)*2);
        const float db0 = db.x * sqdt;       // dB_all = dBt * sqrt(dt)
        const float db1 = db.y * sqdt;
        const float dp0 = s2d * db0;         // dpolar
        const float dp1 = s2d * db1;
        const float X = xsT[(3*p + 0)*SX + e];
        const float Y = xsT[(3*p + 1)*SX + e];
        const float Z = xsT[(3*p + 2)*SX + e];
        const float zc = fminf(fmaxf(Z, -0.999999f), 0.999999f);
        const float theta = acosf(zc);
        const float phi = atan2f(Y, X);
        const float aa = theta - PIO2F;
        const float ca = cosf(aa), sa = sinf(aa);
        const float cp = cosf(phi), sp = sinf(phi);
        const float th = dp0 + PIO2F;
        const float st = sinf(th);
        const float e0v = st * cosf(dp1) - 1.0f;
        const float e1v = st * sinf(dp1);
        const float e2v = cosf(th);
        const float d0 = cp*ca*e0v - sp*e1v + cp*sa*e2v;
        const float d1 = sp*ca*e0v + cp*e1v + sp*sa*e2v;
        const float d2 = -sa*e0v + ca*e2v;
        float Xn = X + runf*d0;
        float Yn = Y + runf*d1;
        float Zn = Z + runf*d2;
        Zn = (Zn < 0.f) ? -Zn : Zn;
        hit |= (Zn < 0.05f) ? 1 : 0;
        psum += Xn + Yn + Zn;
        const float g0 = gbuf[e*96 + 3*p + 0];
        const float g1 = gbuf[e*96 + 3*p + 1];
        const float g2 = gbuf[e*96 + 3*p + 2];
        const float r1 = -g0*sp + g1*cp;
        const float r2 = g0*cp*sa + g1*sp*sa + g2*ca;
        dpsum += (-r2)*dp0 + r1*dp1;
        xsT[(3*p + 0)*SX + e] = Xn;
        xsT[(3*p + 1)*SX + e] = Yn;
        xsT[(3*p + 2)*SX + e] = Zn;
    }
    #pragma unroll
    for (int m = 1; m <= 8; m <<= 1) {
        dpsum += __shfl_xor(dpsum, m);
        psum  += __shfl_xor(psum, m);
        hit   |= __shfl_xor(hit, m);
    }
    if (tt == 0) {
        const float pv = sP[e];
        const float rv = sRun[e];
        const float dp = -(0.2f * pv) * 0.01f + dpsum;   // -f_val*dt + sum
        sP[e] = pv + dp * rv;
        const bool rb = rv > 0.5f;
        if (rb && hit) sRel[e] = psum / 96.0f;           // _pc at hit
        sRun[e] = (rb && !hit) ? 1.0f : 0.0f;
    }
}

__global__ __launch_bounds__(256)
void sphere_ibsde_kernel(
    const float* __restrict__ x0,  const float* __restrict__ dBt,
    const float* __restrict__ Dv,
    const float* __restrict__ pW1, const float* __restrict__ pb1,
    const float* __restrict__ pW2, const float* __restrict__ pb2,
    const float* __restrict__ pW3, const float* __restrict__ pb3,
    const float* __restrict__ gW1, const float* __restrict__ gb1,
    const float* __restrict__ gW2, const float* __restrict__ gb2,
    const float* __restrict__ gW3, const float* __restrict__ gb3,
    float* __restrict__ out)
{
    __shared__ float xsT[DIM3 * SX];     // positions, [k][e]
    __shared__ float h1T[HID * SH];
    __shared__ float h2T[HID * SH];
    __shared__ float wbuf[16 * 256];     // weight chunk; layer3's gbuf aliases this
    __shared__ float sP[NE], sRun[NE], sRel[NE];

    const int tid = threadIdx.x;
    const int b0 = blockIdx.x * NE;

    // load x0 -> xsT transposed
    #pragma unroll
    for (int i = 0; i < 6; ++i) {
        const int f = tid + i*256;
        const int e = f / 96, k = f - e*96;
        xsT[k*SX + e] = x0[(size_t)b0*96 + f];
    }
    // (layer256's internal leading barrier makes xsT visible before any read)

    // ---- p0 = pMLP(x0) ----
    layer256(96,  pW1, pb1, xsT, SX, h1T, wbuf, tid);
    layer256(256, pW2, pb2, h1T, SH, h2T, wbuf, tid);
    __syncthreads();
    {
        const int e = tid >> 4, tt = tid & 15;
        float s = 0.f;
        #pragma unroll
        for (int i = 0; i < 16; ++i) {
            const int k = tt + (i << 4);
            s += h2T[k*SH + e] * pW3[k];
        }
        #pragma unroll
        for (int m = 1; m <= 8; m <<= 1) s += __shfl_xor(s, m);
        if (tt == 0) { sP[e] = s + pb3[0]; sRun[e] = 1.0f; sRel[e] = 0.0f; }
    }

    const int ttc = tid & 15;
    const float s2d0 = sqrtf(2.0f * Dv[ttc]);
    const float s2d1 = sqrtf(2.0f * Dv[ttc + 16]);
    const float sqdt = sqrtf(0.01f);

    // ---- 100 scan steps, entirely block-local ----
    for (int t = 0; t < NSTEPS; ++t) {
        layer256(96,  gW1 + (size_t)t*96*256,  gb1 + (size_t)t*256, xsT, SX, h1T, wbuf, tid);
        layer256(256, gW2 + (size_t)t*256*256, gb2 + (size_t)t*256, h1T, SH, h2T, wbuf, tid);
        layer3(gW3 + (size_t)t*256*96, gb3 + (size_t)t*96, h2T, wbuf, wbuf, tid);
        particles_step(t, b0, dBt, s2d0, s2d1, sqdt, xsT, wbuf, sP, sRun, sRel, tid);
    }

    // ---- finalize ----
    __syncthreads();
    {
        const int e = tid >> 4, tt = tid & 15;
        const int b = b0 + e;
        float s = 0.f;
        #pragma unroll
        for (int i = 0; i < 6; ++i) s += xsT[(tt*6 + i)*SX + e];
        #pragma unroll
        for (int m = 1; m <= 8; m <<= 1) s += __shfl_xor(s, m);
        if (tt == 0) {
            out[2*b] = sP[e];
            float pr = sRel[e];
            if (sRun[e] > 0.5f) pr = s / 96.0f;
            out[2*b + 1] = pr;
        }
    }
}

extern "C" void kernel_launch(void* const* d_in, const int* in_sizes, int n_in,
                              void* d_out, int out_size, void* d_ws, size_t ws_size,
                              hipStream_t stream)
{
    const float* x0  = (const float*)d_in[0];
    const float* dBt = (const float*)d_in[1];
    const float* Dv  = (const float*)d_in[2];
    const float* pW1 = (const float*)d_in[3];
    const float* pb1 = (const float*)d_in[4];
    const float* pW2 = (const float*)d_in[5];
    const float* pb2 = (const float*)d_in[6];
    const float* pW3 = (const float*)d_in[7];
    const float* pb3 = (const float*)d_in[8];
    const float* gW1 = (const float*)d_in[9];
    const float* gb1 = (const float*)d_in[10];
    const float* gW2 = (const float*)d_in[11];
    const float* gb2 = (const float*)d_in[12];
    const float* gW3 = (const float*)d_in[13];
    const float* gb3 = (const float*)d_in[14];
    float* out = (float*)d_out;

    sphere_ibsde_kernel<<<dim3(BATCH / NE), dim3(256), 0, stream>>>(
        x0, dBt, Dv, pW1, pb1, pW2, pb2, pW3, pb3,
        gW1, gb1, gW2, gb2, gW3, gb3, out);
}

// Round 2
// 2294.385 us; speedup vs baseline: 2.0338x; 2.0338x over previous
//
#include <hip/hip_runtime.h>
#include <cstddef>

typedef short bfx8 __attribute__((ext_vector_type(8)));
typedef float f32x4 __attribute__((ext_vector_type(4)));

#define BATCH   4096
#define DXP     32
#define DIM3    96
#define NSTEPS  100
#define HID     256
#define NE      16
#define KS      264     // A-buffer row stride in bf16 elems (pad breaks bank alignment)
#define XS      100     // xsF/gbuf row stride in floats
#define PIO2F   1.57079632679489662f

__device__ __forceinline__ unsigned short f2bf(float v){
    unsigned u = __float_as_uint(v);
    u += 0x7FFFu + ((u >> 16) & 1u);          // RNE
    return (unsigned short)(u >> 16);
}
__device__ __forceinline__ float bf2f(unsigned short h){
    return __uint_as_float(((unsigned)h) << 16);
}

// =====================================================================
// Prep: weights [T][K][N] fp32 -> transposed split-bf16 hi/lo [T][N][K]
// =====================================================================
__global__ void prep_split_t(const float* __restrict__ in,
                             short* __restrict__ oh, short* __restrict__ ol,
                             int T, int K, int N)
{
    const long total  = (long)T * K * N;
    const long stride = (long)gridDim.x * blockDim.x;
    for (long idx = (long)blockIdx.x * blockDim.x + threadIdx.x; idx < total; idx += stride) {
        long t   = idx / ((long)N * K);
        long rem = idx - t * (long)N * K;
        int  n   = (int)(rem / K);
        int  k   = (int)(rem - (long)n * K);
        float v  = in[((long)t * K + k) * N + n];
        unsigned short h = f2bf(v);
        oh[idx] = (short)h;
        ol[idx] = (short)f2bf(v - bf2f(h));
    }
}

// =====================================================================
// MFMA hidden layer: 16e x 256j, K = KC*32, tanh, split-bf16 out.
// A from LDS [e][k] (stride KS); B from GLOBAL, transposed [n][k] hi/lo.
// Wave w owns j-tiles w*4 .. w*4+3 (16 j each).
// =====================================================================
template<int KC>
__device__ __forceinline__ void layer_hidden(
    const short* __restrict__ Wh, const short* __restrict__ Wl,
    const float* __restrict__ bias,
    const short* __restrict__ inH, const short* __restrict__ inL,
    short* __restrict__ outH, short* __restrict__ outL,
    int lane, int wid)
{
    const int m = lane & 15, q = lane >> 4;
    const int K = KC * 32;

    const short* bph[4]; const short* bpl[4];
    #pragma unroll
    for (int jt = 0; jt < 4; ++jt) {
        const int cj = wid*64 + jt*16 + m;
        bph[jt] = Wh + ((size_t)cj * K + q*8);
        bpl[jt] = Wl + ((size_t)cj * K + q*8);
    }
    f32x4 acc[4];
    #pragma unroll
    for (int jt = 0; jt < 4; ++jt) acc[jt] = (f32x4){0.f,0.f,0.f,0.f};

    bfx8 bh[4], bl[4];
    #pragma unroll
    for (int jt = 0; jt < 4; ++jt) { bh[jt] = *(const bfx8*)bph[jt]; bl[jt] = *(const bfx8*)bpl[jt]; }

    __syncthreads();   // in-buffer written, out-buffer's prior readers done

    const short* aph = inH + m*KS + q*8;
    const short* apl = inL + m*KS + q*8;

    #pragma unroll
    for (int kc = 0; kc < KC; ++kc) {
        const bfx8 ah = *(const bfx8*)(aph + kc*32);
        const bfx8 al = *(const bfx8*)(apl + kc*32);
        bfx8 nh[4], nl[4];
        if (kc + 1 < KC) {
            #pragma unroll
            for (int jt = 0; jt < 4; ++jt) {
                nh[jt] = *(const bfx8*)(bph[jt] + (kc+1)*32);
                nl[jt] = *(const bfx8*)(bpl[jt] + (kc+1)*32);
            }
        }
        #pragma unroll
        for (int jt = 0; jt < 4; ++jt) {
            acc[jt] = __builtin_amdgcn_mfma_f32_16x16x32_bf16(ah, bh[jt], acc[jt], 0, 0, 0);
            acc[jt] = __builtin_amdgcn_mfma_f32_16x16x32_bf16(al, bh[jt], acc[jt], 0, 0, 0);
            acc[jt] = __builtin_amdgcn_mfma_f32_16x16x32_bf16(ah, bl[jt], acc[jt], 0, 0, 0);
        }
        if (kc + 1 < KC) {
            #pragma unroll
            for (int jt = 0; jt < 4; ++jt) { bh[jt] = nh[jt]; bl[jt] = nl[jt]; }
        }
    }
    // epilogue: C layout col=lane&15, row=quad*4+r
    #pragma unroll
    for (int jt = 0; jt < 4; ++jt) {
        const int cj = wid*64 + jt*16 + m;
        const float bv = bias[cj];
        #pragma unroll
        for (int r = 0; r < 4; ++r) {
            const float v = tanhf(acc[jt][r] + bv);
            const unsigned short h = f2bf(v);
            const int row = q*4 + r;
            outH[row*KS + cj] = (short)h;
            outL[row*KS + cj] = (short)f2bf(v - bf2f(h));
        }
    }
}

// =====================================================================
// pMLP layer2 fused with pW3 dot: no h2 materialization.
// =====================================================================
__device__ __forceinline__ void p_l2_dot(
    const short* __restrict__ Wh, const short* __restrict__ Wl,
    const float* __restrict__ pb2, const float* __restrict__ pW3,
    const short* __restrict__ inH, const short* __restrict__ inL,
    float* __restrict__ sPpart, int lane, int wid)
{
    const int m = lane & 15, q = lane >> 4;

    const short* bph[4]; const short* bpl[4];
    #pragma unroll
    for (int jt = 0; jt < 4; ++jt) {
        const int cj = wid*64 + jt*16 + m;
        bph[jt] = Wh + ((size_t)cj * 256 + q*8);
        bpl[jt] = Wl + ((size_t)cj * 256 + q*8);
    }
    f32x4 acc[4];
    #pragma unroll
    for (int jt = 0; jt < 4; ++jt) acc[jt] = (f32x4){0.f,0.f,0.f,0.f};

    __syncthreads();

    const short* aph = inH + m*KS + q*8;
    const short* apl = inL + m*KS + q*8;

    #pragma unroll
    for (int kc = 0; kc < 8; ++kc) {
        const bfx8 ah = *(const bfx8*)(aph + kc*32);
        const bfx8 al = *(const bfx8*)(apl + kc*32);
        #pragma unroll
        for (int jt = 0; jt < 4; ++jt) {
            const bfx8 bh = *(const bfx8*)(bph[jt] + kc*32);
            const bfx8 bl = *(const bfx8*)(bpl[jt] + kc*32);
            acc[jt] = __builtin_amdgcn_mfma_f32_16x16x32_bf16(ah, bh, acc[jt], 0, 0, 0);
            acc[jt] = __builtin_amdgcn_mfma_f32_16x16x32_bf16(al, bh, acc[jt], 0, 0, 0);
            acc[jt] = __builtin_amdgcn_mfma_f32_16x16x32_bf16(ah, bl, acc[jt], 0, 0, 0);
        }
    }
    float ps[4] = {0.f, 0.f, 0.f, 0.f};
    #pragma unroll
    for (int jt = 0; jt < 4; ++jt) {
        const int cj = wid*64 + jt*16 + m;
        const float bv = pb2[cj];
        const float w3 = pW3[cj];
        #pragma unroll
        for (int r = 0; r < 4; ++r)
            ps[r] += tanhf(acc[jt][r] + bv) * w3;
    }
    #pragma unroll
    for (int mask = 1; mask <= 8; mask <<= 1) {
        #pragma unroll
        for (int r = 0; r < 4; ++r) ps[r] += __shfl_xor(ps[r], mask);
    }
    if (m == 0) {
        #pragma unroll
        for (int r = 0; r < 4; ++r) sPpart[wid*16 + q*4 + r] = ps[r];
    }
}

// =====================================================================
// Layer 3: 16e x 96o, K=256, no act, fp32 out to gbuf [e][o] stride XS.
// 6 j-tiles: wave w does jt = w, w+4.
// =====================================================================
__device__ __forceinline__ void layer_out(
    const short* __restrict__ Wh, const short* __restrict__ Wl,
    const float* __restrict__ bias,
    const short* __restrict__ inH, const short* __restrict__ inL,
    float* __restrict__ gbuf, int lane, int wid)
{
    const int m = lane & 15, q = lane >> 4;
    __syncthreads();
    const short* aph = inH + m*KS + q*8;
    const short* apl = inL + m*KS + q*8;
    for (int jt = wid; jt < 6; jt += 4) {
        const int cj = jt*16 + m;
        const short* bph = Wh + ((size_t)cj * 256 + q*8);
        const short* bpl = Wl + ((size_t)cj * 256 + q*8);
        f32x4 acc = (f32x4){0.f,0.f,0.f,0.f};
        #pragma unroll
        for (int kc = 0; kc < 8; ++kc) {
            const bfx8 ah = *(const bfx8*)(aph + kc*32);
            const bfx8 al = *(const bfx8*)(apl + kc*32);
            const bfx8 bh = *(const bfx8*)(bph + kc*32);
            const bfx8 bl = *(const bfx8*)(bpl + kc*32);
            acc = __builtin_amdgcn_mfma_f32_16x16x32_bf16(ah, bh, acc, 0, 0, 0);
            acc = __builtin_amdgcn_mfma_f32_16x16x32_bf16(al, bh, acc, 0, 0, 0);
            acc = __builtin_amdgcn_mfma_f32_16x16x32_bf16(ah, bl, acc, 0, 0, 0);
        }
        const float bv = bias[cj];
        #pragma unroll
        for (int r = 0; r < 4; ++r)
            gbuf[(q*4 + r)*XS + cj] = acc[r] + bv;
    }
}

// =====================================================================
// Particle / SDE update (fp32 exact, contract off). Writes new x to
// xsF (fp32) and split-bf16 into the layer-1 input buffer.
// =====================================================================
__device__ __forceinline__ void particles_step2(
    int t, int b0, const float* __restrict__ dBt,
    float s2d0, float s2d1, float sqdt,
    float* __restrict__ xsF, const float* __restrict__ gbuf,
    short* __restrict__ xH, short* __restrict__ xL,
    float* __restrict__ sP, float* __restrict__ sRun, float* __restrict__ sRel,
    int tid)
{
#pragma clang fp contract(off)
    const int e  = tid >> 4;
    const int tt = tid & 15;
    const int b  = b0 + e;
    const float runf = sRun[e];
    float dpsum = 0.f, psum = 0.f;
    int hit = 0;
    #pragma unroll
    for (int pp = 0; pp < 2; ++pp) {
        const int p = tt + (pp << 4);
        const float s2d = pp ? s2d1 : s2d0;
        const float2 db = *(const float2*)(dBt + (((size_t)t*BATCH + b)*DXP + p)*2);
        const float db0 = db.x * sqdt;
        const float db1 = db.y * sqdt;
        const float dp0 = s2d * db0;
        const float dp1 = s2d * db1;
        const float X = xsF[e*XS + 3*p + 0];
        const float Y = xsF[e*XS + 3*p + 1];
        const float Z = xsF[e*XS + 3*p + 2];
        const float zc = fminf(fmaxf(Z, -0.999999f), 0.999999f);
        const float theta = acosf(zc);
        const float phi = atan2f(Y, X);
        const float aa = theta - PIO2F;
        const float ca = cosf(aa), sa = sinf(aa);
        const float cp = cosf(phi), sp = sinf(phi);
        const float th = dp0 + PIO2F;
        const float st = sinf(th);
        const float e0v = st * cosf(dp1) - 1.0f;
        const float e1v = st * sinf(dp1);
        const float e2v = cosf(th);
        const float d0 = cp*ca*e0v - sp*e1v + cp*sa*e2v;
        const float d1 = sp*ca*e0v + cp*e1v + sp*sa*e2v;
        const float d2 = -sa*e0v + ca*e2v;
        float Xn = X + runf*d0;
        float Yn = Y + runf*d1;
        float Zn = Z + runf*d2;
        Zn = (Zn < 0.f) ? -Zn : Zn;
        hit |= (Zn < 0.05f) ? 1 : 0;
        psum += Xn + Yn + Zn;
        const float g0 = gbuf[e*XS + 3*p + 0];
        const float g1 = gbuf[e*XS + 3*p + 1];
        const float g2 = gbuf[e*XS + 3*p + 2];
        const float r1 = -g0*sp + g1*cp;
        const float r2 = g0*cp*sa + g1*sp*sa + g2*ca;
        dpsum += (-r2)*dp0 + r1*dp1;
        xsF[e*XS + 3*p + 0] = Xn;
        xsF[e*XS + 3*p + 1] = Yn;
        xsF[e*XS + 3*p + 2] = Zn;
        // split-bf16 copy for next step's layer-1 A operand
        const float nv[3] = {Xn, Yn, Zn};
        #pragma unroll
        for (int c = 0; c < 3; ++c) {
            const unsigned short h = f2bf(nv[c]);
            xH[e*KS + 3*p + c] = (short)h;
            xL[e*KS + 3*p + c] = (short)f2bf(nv[c] - bf2f(h));
        }
    }
    #pragma unroll
    for (int mask = 1; mask <= 8; mask <<= 1) {
        dpsum += __shfl_xor(dpsum, mask);
        psum  += __shfl_xor(psum, mask);
        hit   |= __shfl_xor(hit, mask);
    }
    if (tt == 0) {
        const float pv = sP[e];
        const float rv = sRun[e];
        const float dp = -(0.2f * pv) * 0.01f + dpsum;
        sP[e] = pv + dp * rv;
        const bool rb = rv > 0.5f;
        if (rb && hit) sRel[e] = psum / 96.0f;
        sRun[e] = (rb && !hit) ? 1.0f : 0.0f;
    }
}

__global__ __launch_bounds__(256)
void sphere_mfma_kernel(
    const float* __restrict__ x0,  const float* __restrict__ dBt,
    const float* __restrict__ Dv,
    const short* __restrict__ pW1h, const short* __restrict__ pW1l, const float* __restrict__ pb1,
    const short* __restrict__ pW2h, const short* __restrict__ pW2l, const float* __restrict__ pb2,
    const float* __restrict__ pW3,  const float* __restrict__ pb3,
    const short* __restrict__ gW1h, const short* __restrict__ gW1l, const float* __restrict__ gb1,
    const short* __restrict__ gW2h, const short* __restrict__ gW2l, const float* __restrict__ gb2,
    const short* __restrict__ gW3h, const short* __restrict__ gW3l, const float* __restrict__ gb3,
    float* __restrict__ out)
{
    __shared__ short aH0[NE*KS], aL0[NE*KS], aH1[NE*KS], aL1[NE*KS];
    __shared__ float xsF[NE*XS], gbuf[NE*XS];
    __shared__ float sPpart[64];
    __shared__ float sP[NE], sRun[NE], sRel[NE];

    const int tid  = threadIdx.x;
    const int lane = tid & 63, wid = tid >> 6;
    const int b0   = blockIdx.x * NE;

    // x0 -> xsF (fp32) + split-bf16 A buffer
    #pragma unroll
    for (int i = 0; i < 6; ++i) {
        const int f = tid + i*256;
        const int e = f / 96, k = f - e*96;
        const float v = x0[(size_t)b0*96 + f];
        xsF[e*XS + k] = v;
        const unsigned short h = f2bf(v);
        aH0[e*KS + k] = (short)h;
        aL0[e*KS + k] = (short)f2bf(v - bf2f(h));
    }

    // ---- p0 = pMLP(x0), layer2 fused with pW3 dot ----
    layer_hidden<3>(pW1h, pW1l, pb1, aH0, aL0, aH1, aL1, lane, wid);
    p_l2_dot(pW2h, pW2l, pb2, pW3, aH1, aL1, sPpart, lane, wid);
    __syncthreads();
    if (tid < NE) {
        sP[tid] = sPpart[tid] + sPpart[16+tid] + sPpart[32+tid] + sPpart[48+tid] + pb3[0];
        sRun[tid] = 1.0f; sRel[tid] = 0.0f;
    }

    const int ttc = tid & 15;
    const float s2d0 = sqrtf(2.0f * Dv[ttc]);
    const float s2d1 = sqrtf(2.0f * Dv[ttc + 16]);
    const float sqdt = sqrtf(0.01f);

    // ---- 100 scan steps, 4 barriers each ----
    for (int t = 0; t < NSTEPS; ++t) {
        layer_hidden<3>(gW1h + (size_t)t*24576, gW1l + (size_t)t*24576,
                        gb1 + (size_t)t*256, aH0, aL0, aH1, aL1, lane, wid);
        layer_hidden<8>(gW2h + (size_t)t*65536, gW2l + (size_t)t*65536,
                        gb2 + (size_t)t*256, aH1, aL1, aH0, aL0, lane, wid);
        layer_out(gW3h + (size_t)t*24576, gW3l + (size_t)t*24576,
                  gb3 + (size_t)t*96, aH0, aL0, gbuf, lane, wid);
        __syncthreads();
        particles_step2(t, b0, dBt, s2d0, s2d1, sqdt, xsF, gbuf, aH0, aL0,
                        sP, sRun, sRel, tid);
    }

    // ---- finalize ----
    __syncthreads();
    {
        const int e = tid >> 4, tt = tid & 15;
        const int b = b0 + e;
        float s = 0.f;
        #pragma unroll
        for (int i = 0; i < 6; ++i) s += xsF[e*XS + tt*6 + i];
        #pragma unroll
        for (int mask = 1; mask <= 8; mask <<= 1) s += __shfl_xor(s, mask);
        if (tt == 0) {
            out[2*b] = sP[e];
            float pr = sRel[e];
            if (sRun[e] > 0.5f) pr = s / 96.0f;
            out[2*b + 1] = pr;
        }
    }
}

// =====================================================================
// ===================== FALLBACK (round-1 kernel) =====================
// Used only if ws_size is too small for the split-bf16 weights.
// =====================================================================
#define SH 20
#define SX 16

__device__ __forceinline__ void layer256_fb(
    int K, const float* __restrict__ W, const float* __restrict__ bias,
    const float* __restrict__ in_lds, int in_stride,
    float* __restrict__ out_lds, float* __restrict__ wbuf, int tid)
{
    const int jg = tid & 63;
    const int eg = tid >> 6;
    const int j0 = jg << 2;
    const int e0 = eg << 2;
    float acc[4][4];
    #pragma unroll
    for (int ee = 0; ee < 4; ++ee)
        #pragma unroll
        for (int jj = 0; jj < 4; ++jj) acc[ee][jj] = 0.f;
    const int nc = K >> 4;
    const float4* __restrict__ Wv = (const float4*)W;
    float4* wv = (float4*)wbuf;
    float4 pre[4];
    #pragma unroll
    for (int i = 0; i < 4; ++i) pre[i] = Wv[tid + i*256];
    for (int c = 0; c < nc; ++c) {
        __syncthreads();
        #pragma unroll
        for (int i = 0; i < 4; ++i) wv[tid + i*256] = pre[i];
        if (c + 1 < nc) {
            #pragma unroll
            for (int i = 0; i < 4; ++i) pre[i] = Wv[(c+1)*1024 + tid + i*256];
        }
        __syncthreads();
        const float* inb = in_lds + (c << 4) * in_stride + e0;
        #pragma unroll
        for (int kk = 0; kk < 16; ++kk) {
            const float4 a = *(const float4*)(inb + kk * in_stride);
            const float4 w = *(const float4*)(wbuf + kk*256 + j0);
            const float av[4] = {a.x, a.y, a.z, a.w};
            const float wl[4] = {w.x, w.y, w.z, w.w};
            #pragma unroll
            for (int ee = 0; ee < 4; ++ee)
                #pragma unroll
                for (int jj = 0; jj < 4; ++jj)
                    acc[ee][jj] += av[ee] * wl[jj];
        }
    }
    const float4 bb = *(const float4*)(bias + j0);
    const float bv[4] = {bb.x, bb.y, bb.z, bb.w};
    #pragma unroll
    for (int jj = 0; jj < 4; ++jj) {
        float4 v;
        v.x = tanhf(acc[0][jj] + bv[jj]);
        v.y = tanhf(acc[1][jj] + bv[jj]);
        v.z = tanhf(acc[2][jj] + bv[jj]);
        v.w = tanhf(acc[3][jj] + bv[jj]);
        *(float4*)(out_lds + (j0 + jj) * SH + e0) = v;
    }
}

__device__ __forceinline__ void layer3_fb(
    const float* __restrict__ W, const float* __restrict__ bias,
    const float* __restrict__ h2, float* __restrict__ wbuf,
    float* __restrict__ gbuf, int tid)
{
    const int og = tid & 31;
    const int eg = tid >> 5;
    const int o0 = og * 3;
    const int e0 = eg << 1;
    float acc[2][3];
    #pragma unroll
    for (int ee = 0; ee < 2; ++ee)
        #pragma unroll
        for (int oo = 0; oo < 3; ++oo) acc[ee][oo] = 0.f;
    const float2* __restrict__ Wv = (const float2*)W;
    float2* wv2 = (float2*)wbuf;
    float2 pre[3];
    #pragma unroll
    for (int i = 0; i < 3; ++i) pre[i] = Wv[tid + i*256];
    for (int c = 0; c < 16; ++c) {
        __syncthreads();
        #pragma unroll
        for (int i = 0; i < 3; ++i) wv2[tid + i*256] = pre[i];
        if (c + 1 < 16) {
            #pragma unroll
            for (int i = 0; i < 3; ++i) pre[i] = Wv[(c+1)*768 + tid + i*256];
        }
        __syncthreads();
        #pragma unroll
        for (int kk = 0; kk < 16; ++kk) {
            const float2 a = *(const float2*)(h2 + (c*16 + kk)*SH + e0);
            const float* wr = wbuf + kk*96 + o0;
            const float w0 = wr[0], w1 = wr[1], w2 = wr[2];
            acc[0][0] += a.x*w0; acc[0][1] += a.x*w1; acc[0][2] += a.x*w2;
            acc[1][0] += a.y*w0; acc[1][1] += a.y*w1; acc[1][2] += a.y*w2;
        }
    }
    __syncthreads();
    #pragma unroll
    for (int ee = 0; ee < 2; ++ee)
        #pragma unroll
        for (int oo = 0; oo < 3; ++oo)
            gbuf[(e0 + ee)*96 + o0 + oo] = acc[ee][oo] + bias[o0 + oo];
    __syncthreads();
}

__device__ __forceinline__ void particles_step_fb(
    int t, int b0, const float* __restrict__ dBt,
    float s2d0, float s2d1, float sqdt,
    float* __restrict__ xsT, const float* __restrict__ gbuf,
    float* __restrict__ sP, float* __restrict__ sRun, float* __restrict__ sRel,
    int tid)
{
#pragma clang fp contract(off)
    const int e  = tid >> 4;
    const int tt = tid & 15;
    const int b  = b0 + e;
    const float runf = sRun[e];
    float dpsum = 0.f, psum = 0.f;
    int hit = 0;
    #pragma unroll
    for (int pp = 0; pp < 2; ++pp) {
        const int p = tt + (pp << 4);
        const float s2d = pp ? s2d1 : s2d0;
        const float2 db = *(const float2*)(dBt + (((size_t)t*BATCH + b)*DXP + p)*2);
        const float db0 = db.x * sqdt;
        const float db1 = db.y * sqdt;
        const float dp0 = s2d * db0;
        const float dp1 = s2d * db1;
        const float X = xsT[(3*p + 0)*SX + e];
        const float Y = xsT[(3*p + 1)*SX + e];
        const float Z = xsT[(3*p + 2)*SX + e];
        const float zc = fminf(fmaxf(Z, -0.999999f), 0.999999f);
        const float theta = acosf(zc);
        const float phi = atan2f(Y, X);
        const float aa = theta - PIO2F;
        const float ca = cosf(aa), sa = sinf(aa);
        const float cp = cosf(phi), sp = sinf(phi);
        const float th = dp0 + PIO2F;
        const float st = sinf(th);
        const float e0v = st * cosf(dp1) - 1.0f;
        const float e1v = st * sinf(dp1);
        const float e2v = cosf(th);
        const float d0 = cp*ca*e0v - sp*e1v + cp*sa*e2v;
        const float d1 = sp*ca*e0v + cp*e1v + sp*sa*e2v;
        const float d2 = -sa*e0v + ca*e2v;
        float Xn = X + runf*d0;
        float Yn = Y + runf*d1;
        float Zn = Z + runf*d2;
        Zn = (Zn < 0.f) ? -Zn : Zn;
        hit |= (Zn < 0.05f) ? 1 : 0;
        psum += Xn + Yn + Zn;
        const float g0 = gbuf[e*96 + 3*p + 0];
        const float g1 = gbuf[e*96 + 3*p + 1];
        const float g2 = gbuf[e*96 + 3*p + 2];
        const float r1 = -g0*sp + g1*cp;
        const float r2 = g0*cp*sa + g1*sp*sa + g2*ca;
        dpsum += (-r2)*dp0 + r1*dp1;
        xsT[(3*p + 0)*SX + e] = Xn;
        xsT[(3*p + 1)*SX + e] = Yn;
        xsT[(3*p + 2)*SX + e] = Zn;
    }
    #pragma unroll
    for (int m = 1; m <= 8; m <<= 1) {
        dpsum += __shfl_xor(dpsum, m);
        psum  += __shfl_xor(psum, m);
        hit   |= __shfl_xor(hit, m);
    }
    if (tt == 0) {
        const float pv = sP[e];
        const float rv = sRun[e];
        const float dp = -(0.2f * pv) * 0.01f + dpsum;
        sP[e] = pv + dp * rv;
        const bool rb = rv > 0.5f;
        if (rb && hit) sRel[e] = psum / 96.0f;
        sRun[e] = (rb && !hit) ? 1.0f : 0.0f;
    }
}

__global__ __launch_bounds__(256)
void sphere_ibsde_kernel_fb(
    const float* __restrict__ x0,  const float* __restrict__ dBt,
    const float* __restrict__ Dv,
    const float* __restrict__ pW1, const float* __restrict__ pb1,
    const float* __restrict__ pW2, const float* __restrict__ pb2,
    const float* __restrict__ pW3, const float* __restrict__ pb3,
    const float* __restrict__ gW1, const float* __restrict__ gb1,
    const float* __restrict__ gW2, const float* __restrict__ gb2,
    const float* __restrict__ gW3, const float* __restrict__ gb3,
    float* __restrict__ out)
{
    __shared__ float xsT[DIM3 * SX];
    __shared__ float h1T[HID * SH];
    __shared__ float h2T[HID * SH];
    __shared__ float wbuf[16 * 256];
    __shared__ float sP[NE], sRun[NE], sRel[NE];

    const int tid = threadIdx.x;
    const int b0 = blockIdx.x * NE;

    #pragma unroll
    for (int i = 0; i < 6; ++i) {
        const int f = tid + i*256;
        const int e = f / 96, k = f - e*96;
        xsT[k*SX + e] = x0[(size_t)b0*96 + f];
    }

    layer256_fb(96,  pW1, pb1, xsT, SX, h1T, wbuf, tid);
    layer256_fb(256, pW2, pb2, h1T, SH, h2T, wbuf, tid);
    __syncthreads();
    {
        const int e = tid >> 4, tt = tid & 15;
        float s = 0.f;
        #pragma unroll
        for (int i = 0; i < 16; ++i) {
            const int k = tt + (i << 4);
            s += h2T[k*SH + e] * pW3[k];
        }
        #pragma unroll
        for (int m = 1; m <= 8; m <<= 1) s += __shfl_xor(s, m);
        if (tt == 0) { sP[e] = s + pb3[0]; sRun[e] = 1.0f; sRel[e] = 0.0f; }
    }

    const int ttc = tid & 15;
    const float s2d0 = sqrtf(2.0f * Dv[ttc]);
    const float s2d1 = sqrtf(2.0f * Dv[ttc + 16]);
    const float sqdt = sqrtf(0.01f);

    for (int t = 0; t < NSTEPS; ++t) {
        layer256_fb(96,  gW1 + (size_t)t*96*256,  gb1 + (size_t)t*256, xsT, SX, h1T, wbuf, tid);
        layer256_fb(256, gW2 + (size_t)t*256*256, gb2 + (size_t)t*256, h1T, SH, h2T, wbuf, tid);
        layer3_fb(gW3 + (size_t)t*256*96, gb3 + (size_t)t*96, h2T, wbuf, wbuf, tid);
        particles_step_fb(t, b0, dBt, s2d0, s2d1, sqdt, xsT, wbuf, sP, sRun, sRel, tid);
    }

    __syncthreads();
    {
        const int e = tid >> 4, tt = tid & 15;
        const int b = b0 + e;
        float s = 0.f;
        #pragma unroll
        for (int i = 0; i < 6; ++i) s += xsT[(tt*6 + i)*SX + e];
        #pragma unroll
        for (int m = 1; m <= 8; m <<= 1) s += __shfl_xor(s, m);
        if (tt == 0) {
            out[2*b] = sP[e];
            float pr = sRel[e];
            if (sRun[e] > 0.5f) pr = s / 96.0f;
            out[2*b + 1] = pr;
        }
    }
}

// =====================================================================
extern "C" void kernel_launch(void* const* d_in, const int* in_sizes, int n_in,
                              void* d_out, int out_size, void* d_ws, size_t ws_size,
                              hipStream_t stream)
{
    const float* x0  = (const float*)d_in[0];
    const float* dBt = (const float*)d_in[1];
    const float* Dv  = (const float*)d_in[2];
    const float* pW1 = (const float*)d_in[3];
    const float* pb1 = (const float*)d_in[4];
    const float* pW2 = (const float*)d_in[5];
    const float* pb2 = (const float*)d_in[6];
    const float* pW3 = (const float*)d_in[7];
    const float* pb3 = (const float*)d_in[8];
    const float* gW1 = (const float*)d_in[9];
    const float* gb1 = (const float*)d_in[10];
    const float* gW2 = (const float*)d_in[11];
    const float* gb2 = (const float*)d_in[12];
    const float* gW3 = (const float*)d_in[13];
    const float* gb3 = (const float*)d_in[14];
    float* out = (float*)d_out;

    const size_t A1 = (size_t)NSTEPS*256*96;   // gW1t elems per buffer
    const size_t A2 = (size_t)NSTEPS*256*256;
    const size_t A3 = (size_t)NSTEPS*96*256;
    const size_t P1 = 256*96;
    const size_t P2 = 256*256;
    const size_t total_elems = 2*(A1 + A2 + A3 + P1 + P2);

    if (ws_size >= total_elems * sizeof(short)) {
        short* p = (short*)d_ws;
        short* gW1h = p;            p += A1;
        short* gW1l = p;            p += A1;
        short* gW2h = p;            p += A2;
        short* gW2l = p;            p += A2;
        short* gW3h = p;            p += A3;
        short* gW3l = p;            p += A3;
        short* pW1h = p;            p += P1;
        short* pW1l = p;            p += P1;
        short* pW2h = p;            p += P2;
        short* pW2l = p;            p += P2;

        prep_split_t<<<dim3(1024), dim3(256), 0, stream>>>(gW1, gW1h, gW1l, NSTEPS, 96, 256);
        prep_split_t<<<dim3(2048), dim3(256), 0, stream>>>(gW2, gW2h, gW2l, NSTEPS, 256, 256);
        prep_split_t<<<dim3(1024), dim3(256), 0, stream>>>(gW3, gW3h, gW3l, NSTEPS, 256, 96);
        prep_split_t<<<dim3(64),   dim3(256), 0, stream>>>(pW1, pW1h, pW1l, 1, 96, 256);
        prep_split_t<<<dim3(128),  dim3(256), 0, stream>>>(pW2, pW2h, pW2l, 1, 256, 256);

        sphere_mfma_kernel<<<dim3(BATCH / NE), dim3(256), 0, stream>>>(
            x0, dBt, Dv,
            pW1h, pW1l, pb1, pW2h, pW2l, pb2, pW3, pb3,
            gW1h, gW1l, gb1, gW2h, gW2l, gb2, gW3h, gW3l, gb3, out);
    } else {
        sphere_ibsde_kernel_fb<<<dim3(BATCH / NE), dim3(256), 0, stream>>>(
            x0, dBt, Dv, pW1, pb1, pW2, pb2, pW3, pb3,
            gW1, gb1, gW2, gb2, gW3, gb3, out);
    }
}